// Round 20
// baseline (146.887 us; speedup 1.0000x reference)
//
#include <hip/hip_runtime.h>
#include <math.h>

#define NH   8
#define PP   3
#define HP   24      // NH*PP
#define E    512
#define EK   64
#define D    128
#define LL   2048
#define BB   64
#define TT   1024
#define LAT  256
#define HID  512
#define CH2  16      // l-chunks (128 each) in weighted-sum pass

typedef __attribute__((ext_vector_type(8))) short bf16x8;
typedef __attribute__((ext_vector_type(16))) float f32x16;

// ---- workspace offsets (in floats) ----
#define OFF_VS     ((size_t)2048)         // 1536 (vsin 24x64)
#define OFF_WA     ((size_t)4096)         // 24
#define OFF_WB     ((size_t)4128)         // 24
#define OFF_SB     ((size_t)4160)         // 24
#define OFF_CVP    ((size_t)73728)        // 8192 (cvec partials)
#define OFF_P2     ((size_t)81920)        // 393216 (part2)
#define OFF_PART   ((size_t)475136)       // 3145728 floats = 6291456 ushorts (part, bf16)
#define OFF_SC     ((size_t)3620864)      // (W2F/W3F live here)
#define OFF_A      ((size_t)3784704)      // 98304 (abuf)

__device__ inline ushort f2bf(float x) {
    union { float f; uint u; } v; v.f = x;
    uint r = v.u + 0x7fffu + ((v.u >> 16) & 1u);
    return (ushort)(r >> 16);
}
__device__ inline float bf2f(ushort u) {
    union { uint u; float f; } v; v.u = (uint)u << 16;
    return v.f;
}
__device__ inline uint swz(uint a)  { return a ^ (((a >> 8) & 7u) << 4); }   // 256B rows
__device__ inline uint swzH(uint a) { return a ^ (((a >> 7) & 7u) << 4); }   // 128B rows
__device__ inline uint pk2(float lo, float hi) {
    return (uint)f2bf(lo) | ((uint)f2bf(hi) << 16);
}
__device__ inline float h1f(float a0, float a1, float a2, float t) {
    return fmaxf(fmaf(t, fmaf(t, a2, a1), a0), 0.f);
}
// sigma: D1 row-slot -> j-within-tile (swap bits 2,3 when exactly one set)
__device__ inline int sigma(int s) { return s ^ (((((s >> 2) ^ (s >> 3)) & 1)) ? 12 : 0); }

// K_SETUP (verified R19): q-phase parallel, cvp partials, W2F/W3F convert.
__global__ __launch_bounds__(512) void k_setup(const float* __restrict__ query,
                                               const float* __restrict__ W_q,
                                               const float* __restrict__ b_q,
                                               const float* __restrict__ W_k,
                                               const float* __restrict__ b_k,
                                               const float* __restrict__ w_te,
                                               const float* __restrict__ b_te,
                                               const float* __restrict__ W_o,
                                               const float* __restrict__ W2,
                                               const float* __restrict__ W3,
                                               float* __restrict__ vsin,
                                               float* __restrict__ wA,
                                               float* __restrict__ wB,
                                               float* __restrict__ sbias,
                                               float* __restrict__ cvp,
                                               ushort* __restrict__ W2F,
                                               ushort* __restrict__ W3F) {
    int bx = blockIdx.x, tid = threadIdx.x;
    if (bx < HP) {
        int hp = bx, h = hp / PP, p = hp % PP;
        __shared__ float q_s[EK];
        __shared__ float qp[8][EK];
        {
            int e2 = tid & 63, ig = tid >> 6;
            float pacc = 0.f;
            const float* qr = query + p * E + ig * 64;
            const float* wq = W_q + (size_t)(ig * 64) * E + h * EK + e2;
            #pragma unroll 8
            for (int i = 0; i < 64; ++i)
                pacc = fmaf(qr[i], wq[(size_t)i * E], pacc);
            qp[ig][e2] = pacc;
        }
        __syncthreads();
        if (tid < EK) {
            float acc = b_q[h * EK + tid];
            #pragma unroll
            for (int g = 0; g < 8; ++g) acc += qp[g][tid];
            q_s[tid] = acc;
        }
        __syncthreads();
        int e = tid;
        const float scale = 0.125f;
        float acc = 0.f;
        {
            const float4* wk4 = (const float4*)(W_k + (size_t)e * E + h * EK);
            const float4* qs4 = (const float4*)q_s;
            #pragma unroll 4
            for (int j4 = 0; j4 < 16; ++j4) {
                float4 w4 = wk4[j4], q4 = qs4[j4];
                acc += w4.x * q4.x + w4.y * q4.y + w4.z * q4.z + w4.w * q4.w;
            }
        }
        float v = acc * scale;
        if ((e & 7) == 0) vsin[hp * 64 + (e >> 3)] = v;
        __shared__ float r1[512], r2[512];
        r1[e] = v * w_te[e];
        r2[e] = v * b_te[e];
        __syncthreads();
        for (int s = 256; s > 0; s >>= 1) {
            if (e < s) { r1[e] += r1[e + s]; r2[e] += r2[e + s]; }
            __syncthreads();
        }
        if (e == 0) {
            wA[hp] = r1[0];
            wB[hp] = r2[0];
            float sb = 0.f;
            for (int j = 0; j < EK; ++j) sb += b_k[h * EK + j] * q_s[j];
            sbias[hp] = sb * scale;
        }
    } else if (bx < HP + 32) {
        int bc = bx - HP;           // 0..31
        int h = bc >> 2, cc = bc & 3, o = tid & 255;
        float acc = 0.f;
        #pragma unroll 8
        for (int c = cc * 32; c < cc * 32 + 32; ++c)
            acc += W_o[(size_t)(h * 256 + 128 + c) * LAT + o];
        cvp[(h * 4 + cc) * LAT + o] = acc;
    } else {
        int gid = (bx - HP - 32) * 512 + tid;   // 0..40959
        int l = gid & 63;
        int kb = 8 * (l >> 5);
        int cb = l & 31;
        if (gid < 32768) {
            int F = gid >> 6;
            int JT = F & 15, ks = F >> 4;
            int cbp = sigma(cb);
            int k0 = ks * 16 + kb, j = JT * 32 + cbp;
            #pragma unroll
            for (int e = 0; e < 8; ++e)
                W2F[(size_t)gid * 8 + e] = f2bf(W2[(size_t)(k0 + e) * HID + j]);
        } else {
            int g2 = gid - 32768;
            int F2 = g2 >> 6;
            int CT = F2 & 3, KT = F2 >> 2;
            int k0 = KT * 16 + kb, c = CT * 32 + cb;
            #pragma unroll
            for (int e = 0; e < 8; ++e)
                W3F[(size_t)g2 * 8 + e] = f2bf(W3[(size_t)(k0 + e) * D + c]);
        }
    }
}

// K_WSF v3 (verified R18/R19)
__global__ __launch_bounds__(512, 8) void k_wsf2(const float* __restrict__ timesteps,
                                                 const float* __restrict__ w_te,
                                                 const float* __restrict__ b_te,
                                                 const float* __restrict__ vsin,
                                                 const float* __restrict__ wA,
                                                 const float* __restrict__ wB,
                                                 const float* __restrict__ sb,
                                                 const float* __restrict__ X,
                                                 const float* __restrict__ M,
                                                 ushort* __restrict__ part) {
    __shared__ char sbuf[40960];
    float* vs_s = (float*)sbuf;
    float* w8_s = (float*)(sbuf + 6144);
    float* b8_s = (float*)(sbuf + 6400);
    float* wA_s = (float*)(sbuf + 6656);
    float* wB_s = (float*)(sbuf + 6784);
    float* sb_s = (float*)(sbuf + 6912);
    ushort* vt  = (ushort*)sbuf;
    ushort* w_s = (ushort*)(sbuf + 32768);
    int b = blockIdx.x >> 4, ch = blockIdx.x & 15;
    int l0 = ch * 128;
    int tid = threadIdx.x;

    for (int i = tid; i < HP * 64; i += 512) vs_s[i] = vsin[i];
    if (tid < 64) { w8_s[tid] = w_te[tid * 8]; b8_s[tid] = b_te[tid * 8]; }
    if (tid < HP) { wA_s[tid] = wA[tid]; wB_s[tid] = wB[tid]; sb_s[tid] = sb[tid]; }
    __syncthreads();

    {
        int lpair = tid & 63, hh = tid >> 6;
        float ts0 = timesteps[(size_t)b * LL + l0 + lpair * 2];
        float ts1 = timesteps[(size_t)b * LL + l0 + lpair * 2 + 1];
        float sc0[3], sc1[3];
        #pragma unroll
        for (int i = 0; i < 3; ++i) {
            int hp = hh * 3 + i;
            sc0[i] = fmaf(ts0, wA_s[hp], wB_s[hp]) + sb_s[hp];
            sc1[i] = fmaf(ts1, wA_s[hp], wB_s[hp]) + sb_s[hp];
        }
        for (int jc = 0; jc < 64; jc += 8) {
            float d0[8], d1[8];
            #pragma unroll
            for (int j = 0; j < 8; ++j) {
                float w = w8_s[jc + j], bb = b8_s[jc + j];
                float k0 = fmaf(ts0, w, bb), k1 = fmaf(ts1, w, bb);
                d0[j] = __sinf(k0) - k0;
                d1[j] = __sinf(k1) - k1;
            }
            #pragma unroll
            for (int i = 0; i < 3; ++i) {
                int hp = hh * 3 + i;
                #pragma unroll
                for (int j = 0; j < 8; j += 4) {
                    float4 v4 = *(const float4*)&vs_s[hp * 64 + jc + j];
                    sc0[i] += d0[j] * v4.x + d0[j+1] * v4.y + d0[j+2] * v4.z + d0[j+3] * v4.w;
                    sc1[i] += d1[j] * v4.x + d1[j+1] * v4.y + d1[j+2] * v4.z + d1[j+3] * v4.w;
                }
            }
        }
        #pragma unroll
        for (int i = 0; i < 3; ++i) {
            int hp = hh * 3 + i;
            *(uint*)((char*)w_s + swz((uint)(hp * 256 + lpair * 4))) = pk2(__expf(sc0[i]), __expf(sc1[i]));
        }
        int hp = 24 + (tid >> 6), lp = tid & 63;
        *(uint*)((char*)w_s + swz((uint)(hp * 256 + lp * 4))) = 0u;
    }
    __syncthreads();

    int lane = tid & 63, wv = tid >> 6;
    int l31 = lane & 31, hl = lane >> 5;
    f32x16 acc;
    #pragma unroll
    for (int e = 0; e < 16; ++e) acc[e] = 0.f;

    int cst = tid & 127, lg = tid >> 7;
    for (int q = 0; q < 2; ++q) {
        if (q) __syncthreads();
        #pragma unroll
        for (int i = 0; i < 8; ++i) {
            int ll = lg * 16 + i * 2;
            size_t g0 = ((size_t)b * LL + l0 + q * 64 + ll) * D + cst;
            float m0 = M[g0], m1 = M[g0 + D];
            float x0 = X[g0] * m0, x1 = X[g0 + D] * m1;
            *(uint*)((char*)vt + swzH((uint)(cst * 128 + ll * 2)))         = pk2(x0, x1);
            *(uint*)((char*)vt + swzH((uint)((128 + cst) * 128 + ll * 2))) = pk2(m0, m1);
        }
        __syncthreads();
        #pragma unroll
        for (int ks = 0; ks < 4; ++ks) {
            bf16x8 af = *(const bf16x8*)((char*)w_s + swz((uint)(l31 * 256 + (q * 64 + ks * 16 + hl * 8) * 2)));
            bf16x8 bf_ = *(const bf16x8*)((char*)vt + swzH((uint)((wv * 32 + l31) * 128 + (ks * 16 + hl * 8) * 2)));
            acc = __builtin_amdgcn_mfma_f32_32x32x16_bf16(af, bf_, acc, 0, 0, 0);
        }
    }
    size_t base = ((size_t)(b * CH2 + ch) * HP) * 256;
    #pragma unroll
    for (int reg = 0; reg < 12; ++reg) {
        int hp = (reg & 3) + 8 * (reg >> 2) + 4 * hl;
        part[base + (size_t)hp * 256 + wv * 32 + l31] = f2bf(acc[reg]);
    }
}

// K_MID (verified R19): coefp over 16 bf16 chunks; h==0 folds Cvec.
__global__ __launch_bounds__(256) void k_mid(const ushort* __restrict__ part,
                                             const float* __restrict__ W_o,
                                             const float* __restrict__ cvp,
                                             const float* __restrict__ b_o,
                                             float* __restrict__ part2) {
    int bx = blockIdx.x, tid = threadIdx.x;
    int b = bx >> 3, h = bx & 7;
    __shared__ float ratio[PP][D];
    for (int ii = tid; ii < PP * D; ii += 256) {
        int p = ii >> 7, c = ii & 127;
        int hp = h * PP + p;
        float n = 0.f, d = 0.f;
        for (int ch = 0; ch < CH2; ++ch) {
            size_t base = ((size_t)(b * CH2 + ch) * HP + hp) * 256;
            n += bf2f(part[base + c]);
            d += bf2f(part[base + 128 + c]);
        }
        ratio[p][c] = n / d;
    }
    __syncthreads();
    int o = tid;
    float a0 = 0.f, a1 = 0.f, a2 = 0.f;
    #pragma unroll 4
    for (int c = 0; c < D; ++c) {
        float w = W_o[(size_t)(h * 256 + c) * LAT + o];
        a0 = fmaf(ratio[0][c], w, a0);
        a1 = fmaf(ratio[1][c], w, a1);
        a2 = fmaf(ratio[2][c], w, a2);
    }
    if (h == 0) {
        float cv = b_o[o];
        #pragma unroll 8
        for (int i = 0; i < 32; ++i) cv += cvp[i * LAT + o];
        a0 += cv; a1 += cv; a2 += cv;
    }
    size_t base = (((size_t)b * NH + h) * PP) * LAT + o;
    part2[base]           = a0;
    part2[base + LAT]     = a1;
    part2[base + 2 * LAT] = a2;
}

// K7'' (verified R19)
__global__ __launch_bounds__(128) void k_avec4(const float* __restrict__ part2,
                                               const float* __restrict__ W1,
                                               const float* __restrict__ b1,
                                               float* __restrict__ abuf) {
    int b = blockIdx.x, jq = blockIdx.y, tid = threadIdx.x;
    __shared__ float cf[PP * LAT];
    for (int idx = tid; idx < PP * LAT; idx += 128) {
        int p = idx / LAT, o = idx % LAT;
        float s = 0.f;
        #pragma unroll
        for (int h = 0; h < NH; ++h)
            s += part2[(((size_t)b * NH + h) * PP + p) * LAT + o];
        cf[p * LAT + o] = s;
    }
    __syncthreads();
    int j = jq * 128 + tid;
    float a0 = b1[j], a1 = 0.f, a2 = 0.f;
    #pragma unroll 4
    for (int k = 0; k < LAT; ++k) {
        float w = W1[(size_t)k * HID + j];
        a0 = fmaf(cf[k], w, a0);
        a1 = fmaf(cf[LAT + k], w, a1);
        a2 = fmaf(cf[2 * LAT + k], w, a2);
    }
    abuf[(size_t)b * 3 * HID + j] = a0;
    abuf[(size_t)b * 3 * HID + HID + j] = a1;
    abuf[(size_t)b * 3 * HID + 2 * HID + j] = a2;
}

// K8 v32: 32 rows/block, grid (64,32) = 2048 blocks, LDS 32KB -> 4 blocks/CU (32 waves).
// 8 waves: GEMM1 wave w owns j-tiles {2w, 2w+1} (acc[2], 32 regs).
// Pack -> 32 fragment slices (in-place, same 32KB). GEMM2: wave (ct=w&3, kh=w>>2),
// K split across kh pairs; in-place f32 reduce (slice region dead).
__global__ __launch_bounds__(512, 4) void k_mlp32(const float* __restrict__ abuf,
                                                  const float* __restrict__ yts,
                                                  const ushort* __restrict__ W2F,
                                                  const float* __restrict__ b2,
                                                  const ushort* __restrict__ W3F,
                                                  const float* __restrict__ b3,
                                                  float* __restrict__ out) {
    __shared__ char lds[32768];   // H1 [4 kp][32 r][128 kk] bf16 -> h2 slices -> f32 reduce
    int b = blockIdx.x, t0 = blockIdx.y * 32, tid = threadIdx.x;
    const float* a0p = abuf + (size_t)b * 3 * HID;
    const float* a1p = a0p + HID;
    const float* a2p = a1p + HID;

    // phase A: thread (sr = tid&31, kblk = tid>>5) stages 32 k's (64B contiguous)
    {
        int sr = tid & 31, kblk = tid >> 5;
        int kp = kblk >> 2, ksub = kblk & 3;
        float t = yts[(size_t)b * TT + t0 + sr];
        int k0 = kp * 128 + ksub * 32;
        uint sbase = (uint)(kp * 8192 + sr * 256 + ksub * 64);
        #pragma unroll
        for (int i = 0; i < 4; ++i) {
            int k = k0 + i * 8;
            float4 xa0 = *(const float4*)(a0p + k), xb0 = *(const float4*)(a0p + k + 4);
            float4 xa1 = *(const float4*)(a1p + k), xb1 = *(const float4*)(a1p + k + 4);
            float4 xa2 = *(const float4*)(a2p + k), xb2 = *(const float4*)(a2p + k + 4);
            uint4 pk;
            pk.x = pk2(h1f(xa0.x, xa1.x, xa2.x, t), h1f(xa0.y, xa1.y, xa2.y, t));
            pk.y = pk2(h1f(xa0.z, xa1.z, xa2.z, t), h1f(xa0.w, xa1.w, xa2.w, t));
            pk.z = pk2(h1f(xb0.x, xb1.x, xb2.x, t), h1f(xb0.y, xb1.y, xb2.y, t));
            pk.w = pk2(h1f(xb0.z, xb1.z, xb2.z, t), h1f(xb0.w, xb1.w, xb2.w, t));
            *(uint4*)(lds + swz(sbase + i * 16)) = pk;
        }
    }
    __syncthreads();

    int lane = tid & 63, w = tid >> 6;
    int l31 = lane & 31, hl = lane >> 5;
    int J0 = w * 2;

    // ---- GEMM1 (swapped): acc[2], j-tiles J0, J0+1; rows 0..31 ----
    f32x16 acc[2];
    #pragma unroll
    for (int jt = 0; jt < 2; ++jt) {
        int jT = (J0 + jt) * 32;
        #pragma unroll
        for (int reg = 0; reg < 16; ++reg) {
            int slot = (reg & 3) + 8 * (reg >> 2) + 4 * hl;
            acc[jt][reg] = b2[jT + sigma(slot)];
        }
    }
    #pragma unroll 4
    for (int ks = 0; ks < 32; ++ks) {
        uint base = (uint)((ks >> 3) * 8192 + l31 * 256 + (ks & 7) * 32 + hl * 16);
        bf16x8 bh = *(const bf16x8*)(lds + swz(base));
        #pragma unroll
        for (int jt = 0; jt < 2; ++jt) {
            bf16x8 af = *(const bf16x8*)(W2F + ((size_t)(ks * 16 + J0 + jt) * 64 + lane) * 8);
            acc[jt] = __builtin_amdgcn_mfma_f32_32x32x16_bf16(af, bh, acc[jt], 0, 0, 0);
        }
    }
    __syncthreads();   // all H1 reads done; reuse LDS for h2 fragment slices

    // pack relu(acc) -> 32 slices of 1KB: sg = J*2 + s, addr = sg*1024 + lane*16
    #pragma unroll
    for (int jt = 0; jt < 2; ++jt) {
        int J = J0 + jt;
        #pragma unroll
        for (int s = 0; s < 2; ++s) {
            uint4 uu;
            uu.x = pk2(fmaxf(acc[jt][8 * s + 0], 0.f), fmaxf(acc[jt][8 * s + 1], 0.f));
            uu.y = pk2(fmaxf(acc[jt][8 * s + 2], 0.f), fmaxf(acc[jt][8 * s + 3], 0.f));
            uu.z = pk2(fmaxf(acc[jt][8 * s + 4], 0.f), fmaxf(acc[jt][8 * s + 5], 0.f));
            uu.w = pk2(fmaxf(acc[jt][8 * s + 6], 0.f), fmaxf(acc[jt][8 * s + 7], 0.f));
            *(uint4*)(lds + (uint)((J * 2 + s) * 1024 + lane * 16)) = uu;
        }
    }
    __syncthreads();

    // ---- GEMM2: wave (ct = w&3, kh = w>>2); 16 K-slices each ----
    int ct = w & 3, kh = w >> 2;
    f32x16 acc2;
    {
        float bv = (kh == 0) ? b3[ct * 32 + l31] : 0.f;
        #pragma unroll
        for (int e = 0; e < 16; ++e) acc2[e] = bv;
    }
    #pragma unroll 4
    for (int u = 0; u < 16; ++u) {
        int sg = kh * 16 + u;
        bf16x8 ah = *(const bf16x8*)(lds + (uint)(sg * 1024 + lane * 16));
        bf16x8 bw = *(const bf16x8*)(W3F + ((size_t)(sg * 4 + ct) * 64 + lane) * 8);
        acc2 = __builtin_amdgcn_mfma_f32_32x32x16_bf16(ah, bw, acc2, 0, 0, 0);
    }
    __syncthreads();   // all slice reads done; reuse first 16KB as f32 reduce

    float* red = (float*)lds;
    if (kh == 1) {
        #pragma unroll
        for (int reg = 0; reg < 16; ++reg) {
            int rloc = (reg & 3) + 8 * (reg >> 2) + 4 * hl;
            red[ct * 1024 + rloc * 32 + l31] = acc2[reg];
        }
    }
    __syncthreads();
    if (kh == 0) {
        int c = ct * 32 + l31;
        size_t rowbase = (size_t)b * TT + t0;
        #pragma unroll
        for (int reg = 0; reg < 16; ++reg) {
            int rloc = (reg & 3) + 8 * (reg >> 2) + 4 * hl;
            float v = acc2[reg] + red[ct * 1024 + rloc * 32 + l31];
            out[(rowbase + rloc) * D + c] = v;
        }
    }
}

extern "C" void kernel_launch(void* const* d_in, const int* in_sizes, int n_in,
                              void* d_out, int out_size, void* d_ws, size_t ws_size,
                              hipStream_t stream) {
    const float* timesteps = (const float*)d_in[0];
    const float* X        = (const float*)d_in[1];
    const float* M        = (const float*)d_in[2];
    const float* yts      = (const float*)d_in[3];
    const float* w_te     = (const float*)d_in[4];
    const float* b_te     = (const float*)d_in[5];
    const float* query    = (const float*)d_in[6];
    const float* W_q      = (const float*)d_in[7];
    const float* b_q      = (const float*)d_in[8];
    const float* W_k      = (const float*)d_in[9];
    const float* b_k      = (const float*)d_in[10];
    const float* W_o      = (const float*)d_in[11];
    const float* b_o      = (const float*)d_in[12];
    const float* W1       = (const float*)d_in[13];
    const float* b1       = (const float*)d_in[14];
    const float* W2       = (const float*)d_in[15];
    const float* b2       = (const float*)d_in[16];
    const float* W3       = (const float*)d_in[17];
    const float* b3       = (const float*)d_in[18];
    float* out = (float*)d_out;
    float* ws  = (float*)d_ws;

    float* vsin   = ws + OFF_VS;
    float* wA     = ws + OFF_WA;
    float* wB     = ws + OFF_WB;
    float* sbias  = ws + OFF_SB;
    float* cvp    = ws + OFF_CVP;
    float* part2  = ws + OFF_P2;
    ushort* part  = (ushort*)(ws + OFF_PART);
    float* abuf   = ws + OFF_A;
    ushort* W2F   = (ushort*)(ws + OFF_SC);
    ushort* W3F   = W2F + (size_t)HID * HID;

    hipLaunchKernelGGL(k_setup,  dim3(HP + 32 + 80),  dim3(512), 0, stream,
                       query, W_q, b_q, W_k, b_k, w_te, b_te, W_o, W2, W3,
                       vsin, wA, wB, sbias, cvp, W2F, W3F);
    hipLaunchKernelGGL(k_wsf2,   dim3(BB * CH2),      dim3(512), 0, stream,
                       timesteps, w_te, b_te, vsin, wA, wB, sbias, X, M, part);
    hipLaunchKernelGGL(k_mid,    dim3(BB * NH),       dim3(256), 0, stream,
                       part, W_o, cvp, b_o, part2);
    hipLaunchKernelGGL(k_avec4,  dim3(BB, 4),         dim3(128), 0, stream,
                       part2, W1, b1, abuf);
    hipLaunchKernelGGL(k_mlp32,  dim3(BB, TT / 32),   dim3(512), 0, stream,
                       abuf, yts, W2F, b2, W3F, b3, out);
}

// Round 21
// 133.278 us; speedup vs baseline: 1.1021x; 1.1021x over previous
//
#include <hip/hip_runtime.h>
#include <math.h>

#define NH   8
#define PP   3
#define HP   24      // NH*PP
#define E    512
#define EK   64
#define D    128
#define LL   2048
#define BB   64
#define TT   1024
#define LAT  256
#define HID  512
#define CH2  16      // l-chunks (128 each) in weighted-sum pass

typedef __attribute__((ext_vector_type(8))) short bf16x8;
typedef __attribute__((ext_vector_type(16))) float f32x16;

// ---- workspace offsets (in floats) ----
#define OFF_VS     ((size_t)2048)         // 1536 (vsin 24x64)
#define OFF_WA     ((size_t)4096)         // 24
#define OFF_WB     ((size_t)4128)         // 24
#define OFF_SB     ((size_t)4160)         // 24
#define OFF_CVP    ((size_t)73728)        // 8192 (cvec partials)
#define OFF_P2     ((size_t)81920)        // 393216 (part2)
#define OFF_PART   ((size_t)475136)       // 3145728 floats = 6291456 ushorts (part, bf16)
#define OFF_SC     ((size_t)3620864)      // (W2F/W3F live here)
#define OFF_A      ((size_t)3784704)      // 98304 (abuf)

__device__ inline ushort f2bf(float x) {
    union { float f; uint u; } v; v.f = x;
    uint r = v.u + 0x7fffu + ((v.u >> 16) & 1u);
    return (ushort)(r >> 16);
}
__device__ inline float bf2f(ushort u) {
    union { uint u; float f; } v; v.u = (uint)u << 16;
    return v.f;
}
__device__ inline uint swz(uint a)  { return a ^ (((a >> 8) & 7u) << 4); }   // 256B rows
__device__ inline uint swzH(uint a) { return a ^ (((a >> 7) & 7u) << 4); }   // 128B rows
__device__ inline uint pk2(float lo, float hi) {
    return (uint)f2bf(lo) | ((uint)f2bf(hi) << 16);
}
__device__ inline float h1f(float a0, float a1, float a2, float t) {
    return fmaxf(fmaf(t, fmaf(t, a2, a1), a0), 0.f);
}
// sigma: D1 row-slot -> j-within-tile (swap bits 2,3 when exactly one set)
__device__ inline int sigma(int s) { return s ^ (((((s >> 2) ^ (s >> 3)) & 1)) ? 12 : 0); }

// K_SETUP (verified R19): q-phase parallel, cvp partials, W2F/W3F convert.
__global__ __launch_bounds__(512) void k_setup(const float* __restrict__ query,
                                               const float* __restrict__ W_q,
                                               const float* __restrict__ b_q,
                                               const float* __restrict__ W_k,
                                               const float* __restrict__ b_k,
                                               const float* __restrict__ w_te,
                                               const float* __restrict__ b_te,
                                               const float* __restrict__ W_o,
                                               const float* __restrict__ W2,
                                               const float* __restrict__ W3,
                                               float* __restrict__ vsin,
                                               float* __restrict__ wA,
                                               float* __restrict__ wB,
                                               float* __restrict__ sbias,
                                               float* __restrict__ cvp,
                                               ushort* __restrict__ W2F,
                                               ushort* __restrict__ W3F) {
    int bx = blockIdx.x, tid = threadIdx.x;
    if (bx < HP) {
        int hp = bx, h = hp / PP, p = hp % PP;
        __shared__ float q_s[EK];
        __shared__ float qp[8][EK];
        {
            int e2 = tid & 63, ig = tid >> 6;
            float pacc = 0.f;
            const float* qr = query + p * E + ig * 64;
            const float* wq = W_q + (size_t)(ig * 64) * E + h * EK + e2;
            #pragma unroll 8
            for (int i = 0; i < 64; ++i)
                pacc = fmaf(qr[i], wq[(size_t)i * E], pacc);
            qp[ig][e2] = pacc;
        }
        __syncthreads();
        if (tid < EK) {
            float acc = b_q[h * EK + tid];
            #pragma unroll
            for (int g = 0; g < 8; ++g) acc += qp[g][tid];
            q_s[tid] = acc;
        }
        __syncthreads();
        int e = tid;
        const float scale = 0.125f;
        float acc = 0.f;
        {
            const float4* wk4 = (const float4*)(W_k + (size_t)e * E + h * EK);
            const float4* qs4 = (const float4*)q_s;
            #pragma unroll 4
            for (int j4 = 0; j4 < 16; ++j4) {
                float4 w4 = wk4[j4], q4 = qs4[j4];
                acc += w4.x * q4.x + w4.y * q4.y + w4.z * q4.z + w4.w * q4.w;
            }
        }
        float v = acc * scale;
        if ((e & 7) == 0) vsin[hp * 64 + (e >> 3)] = v;
        __shared__ float r1[512], r2[512];
        r1[e] = v * w_te[e];
        r2[e] = v * b_te[e];
        __syncthreads();
        for (int s = 256; s > 0; s >>= 1) {
            if (e < s) { r1[e] += r1[e + s]; r2[e] += r2[e + s]; }
            __syncthreads();
        }
        if (e == 0) {
            wA[hp] = r1[0];
            wB[hp] = r2[0];
            float sb = 0.f;
            for (int j = 0; j < EK; ++j) sb += b_k[h * EK + j] * q_s[j];
            sbias[hp] = sb * scale;
        }
    } else if (bx < HP + 32) {
        int bc = bx - HP;           // 0..31
        int h = bc >> 2, cc = bc & 3, o = tid & 255;
        float acc = 0.f;
        #pragma unroll 8
        for (int c = cc * 32; c < cc * 32 + 32; ++c)
            acc += W_o[(size_t)(h * 256 + 128 + c) * LAT + o];
        cvp[(h * 4 + cc) * LAT + o] = acc;
    } else {
        int gid = (bx - HP - 32) * 512 + tid;   // 0..40959
        int l = gid & 63;
        int kb = 8 * (l >> 5);
        int cb = l & 31;
        if (gid < 32768) {
            int F = gid >> 6;
            int JT = F & 15, ks = F >> 4;
            int cbp = sigma(cb);
            int k0 = ks * 16 + kb, j = JT * 32 + cbp;
            #pragma unroll
            for (int e = 0; e < 8; ++e)
                W2F[(size_t)gid * 8 + e] = f2bf(W2[(size_t)(k0 + e) * HID + j]);
        } else {
            int g2 = gid - 32768;
            int F2 = g2 >> 6;
            int CT = F2 & 3, KT = F2 >> 2;
            int k0 = KT * 16 + kb, c = CT * 32 + cb;
            #pragma unroll
            for (int e = 0; e < 8; ++e)
                W3F[(size_t)g2 * 8 + e] = f2bf(W3[(size_t)(k0 + e) * D + c]);
        }
    }
}

// K_WSF v3 (verified R18/R19)
__global__ __launch_bounds__(512, 8) void k_wsf2(const float* __restrict__ timesteps,
                                                 const float* __restrict__ w_te,
                                                 const float* __restrict__ b_te,
                                                 const float* __restrict__ vsin,
                                                 const float* __restrict__ wA,
                                                 const float* __restrict__ wB,
                                                 const float* __restrict__ sb,
                                                 const float* __restrict__ X,
                                                 const float* __restrict__ M,
                                                 ushort* __restrict__ part) {
    __shared__ char sbuf[40960];
    float* vs_s = (float*)sbuf;
    float* w8_s = (float*)(sbuf + 6144);
    float* b8_s = (float*)(sbuf + 6400);
    float* wA_s = (float*)(sbuf + 6656);
    float* wB_s = (float*)(sbuf + 6784);
    float* sb_s = (float*)(sbuf + 6912);
    ushort* vt  = (ushort*)sbuf;
    ushort* w_s = (ushort*)(sbuf + 32768);
    int b = blockIdx.x >> 4, ch = blockIdx.x & 15;
    int l0 = ch * 128;
    int tid = threadIdx.x;

    for (int i = tid; i < HP * 64; i += 512) vs_s[i] = vsin[i];
    if (tid < 64) { w8_s[tid] = w_te[tid * 8]; b8_s[tid] = b_te[tid * 8]; }
    if (tid < HP) { wA_s[tid] = wA[tid]; wB_s[tid] = wB[tid]; sb_s[tid] = sb[tid]; }
    __syncthreads();

    {
        int lpair = tid & 63, hh = tid >> 6;
        float ts0 = timesteps[(size_t)b * LL + l0 + lpair * 2];
        float ts1 = timesteps[(size_t)b * LL + l0 + lpair * 2 + 1];
        float sc0[3], sc1[3];
        #pragma unroll
        for (int i = 0; i < 3; ++i) {
            int hp = hh * 3 + i;
            sc0[i] = fmaf(ts0, wA_s[hp], wB_s[hp]) + sb_s[hp];
            sc1[i] = fmaf(ts1, wA_s[hp], wB_s[hp]) + sb_s[hp];
        }
        for (int jc = 0; jc < 64; jc += 8) {
            float d0[8], d1[8];
            #pragma unroll
            for (int j = 0; j < 8; ++j) {
                float w = w8_s[jc + j], bb = b8_s[jc + j];
                float k0 = fmaf(ts0, w, bb), k1 = fmaf(ts1, w, bb);
                d0[j] = __sinf(k0) - k0;
                d1[j] = __sinf(k1) - k1;
            }
            #pragma unroll
            for (int i = 0; i < 3; ++i) {
                int hp = hh * 3 + i;
                #pragma unroll
                for (int j = 0; j < 8; j += 4) {
                    float4 v4 = *(const float4*)&vs_s[hp * 64 + jc + j];
                    sc0[i] += d0[j] * v4.x + d0[j+1] * v4.y + d0[j+2] * v4.z + d0[j+3] * v4.w;
                    sc1[i] += d1[j] * v4.x + d1[j+1] * v4.y + d1[j+2] * v4.z + d1[j+3] * v4.w;
                }
            }
        }
        #pragma unroll
        for (int i = 0; i < 3; ++i) {
            int hp = hh * 3 + i;
            *(uint*)((char*)w_s + swz((uint)(hp * 256 + lpair * 4))) = pk2(__expf(sc0[i]), __expf(sc1[i]));
        }
        int hp = 24 + (tid >> 6), lp = tid & 63;
        *(uint*)((char*)w_s + swz((uint)(hp * 256 + lp * 4))) = 0u;
    }
    __syncthreads();

    int lane = tid & 63, wv = tid >> 6;
    int l31 = lane & 31, hl = lane >> 5;
    f32x16 acc;
    #pragma unroll
    for (int e = 0; e < 16; ++e) acc[e] = 0.f;

    int cst = tid & 127, lg = tid >> 7;
    for (int q = 0; q < 2; ++q) {
        if (q) __syncthreads();
        #pragma unroll
        for (int i = 0; i < 8; ++i) {
            int ll = lg * 16 + i * 2;
            size_t g0 = ((size_t)b * LL + l0 + q * 64 + ll) * D + cst;
            float m0 = M[g0], m1 = M[g0 + D];
            float x0 = X[g0] * m0, x1 = X[g0 + D] * m1;
            *(uint*)((char*)vt + swzH((uint)(cst * 128 + ll * 2)))         = pk2(x0, x1);
            *(uint*)((char*)vt + swzH((uint)((128 + cst) * 128 + ll * 2))) = pk2(m0, m1);
        }
        __syncthreads();
        #pragma unroll
        for (int ks = 0; ks < 4; ++ks) {
            bf16x8 af = *(const bf16x8*)((char*)w_s + swz((uint)(l31 * 256 + (q * 64 + ks * 16 + hl * 8) * 2)));
            bf16x8 bf_ = *(const bf16x8*)((char*)vt + swzH((uint)((wv * 32 + l31) * 128 + (ks * 16 + hl * 8) * 2)));
            acc = __builtin_amdgcn_mfma_f32_32x32x16_bf16(af, bf_, acc, 0, 0, 0);
        }
    }
    size_t base = ((size_t)(b * CH2 + ch) * HP) * 256;
    #pragma unroll
    for (int reg = 0; reg < 12; ++reg) {
        int hp = (reg & 3) + 8 * (reg >> 2) + 4 * hl;
        part[base + (size_t)hp * 256 + wv * 32 + l31] = f2bf(acc[reg]);
    }
}

// K_MID (verified R19): coefp over 16 bf16 chunks; h==0 folds Cvec.
__global__ __launch_bounds__(256) void k_mid(const ushort* __restrict__ part,
                                             const float* __restrict__ W_o,
                                             const float* __restrict__ cvp,
                                             const float* __restrict__ b_o,
                                             float* __restrict__ part2) {
    int bx = blockIdx.x, tid = threadIdx.x;
    int b = bx >> 3, h = bx & 7;
    __shared__ float ratio[PP][D];
    for (int ii = tid; ii < PP * D; ii += 256) {
        int p = ii >> 7, c = ii & 127;
        int hp = h * PP + p;
        float n = 0.f, d = 0.f;
        for (int ch = 0; ch < CH2; ++ch) {
            size_t base = ((size_t)(b * CH2 + ch) * HP + hp) * 256;
            n += bf2f(part[base + c]);
            d += bf2f(part[base + 128 + c]);
        }
        ratio[p][c] = n / d;
    }
    __syncthreads();
    int o = tid;
    float a0 = 0.f, a1 = 0.f, a2 = 0.f;
    #pragma unroll 4
    for (int c = 0; c < D; ++c) {
        float w = W_o[(size_t)(h * 256 + c) * LAT + o];
        a0 = fmaf(ratio[0][c], w, a0);
        a1 = fmaf(ratio[1][c], w, a1);
        a2 = fmaf(ratio[2][c], w, a2);
    }
    if (h == 0) {
        float cv = b_o[o];
        #pragma unroll 8
        for (int i = 0; i < 32; ++i) cv += cvp[i * LAT + o];
        a0 += cv; a1 += cv; a2 += cv;
    }
    size_t base = (((size_t)b * NH + h) * PP) * LAT + o;
    part2[base]           = a0;
    part2[base + LAT]     = a1;
    part2[base + 2 * LAT] = a2;
}

// K7'' (verified R19)
__global__ __launch_bounds__(128) void k_avec4(const float* __restrict__ part2,
                                               const float* __restrict__ W1,
                                               const float* __restrict__ b1,
                                               float* __restrict__ abuf) {
    int b = blockIdx.x, jq = blockIdx.y, tid = threadIdx.x;
    __shared__ float cf[PP * LAT];
    for (int idx = tid; idx < PP * LAT; idx += 128) {
        int p = idx / LAT, o = idx % LAT;
        float s = 0.f;
        #pragma unroll
        for (int h = 0; h < NH; ++h)
            s += part2[(((size_t)b * NH + h) * PP + p) * LAT + o];
        cf[p * LAT + o] = s;
    }
    __syncthreads();
    int j = jq * 128 + tid;
    float a0 = b1[j], a1 = 0.f, a2 = 0.f;
    #pragma unroll 4
    for (int k = 0; k < LAT; ++k) {
        float w = W1[(size_t)k * HID + j];
        a0 = fmaf(cf[k], w, a0);
        a1 = fmaf(cf[LAT + k], w, a1);
        a2 = fmaf(cf[2 * LAT + k], w, a2);
    }
    abuf[(size_t)b * 3 * HID + j] = a0;
    abuf[(size_t)b * 3 * HID + HID + j] = a1;
    abuf[(size_t)b * 3 * HID + 2 * HID + j] = a2;
}

// K8 v12 (byte-exact R19 winner): 64 rows/block, 8 waves = 4 gw x 2 wp.
__global__ __launch_bounds__(512, 4) void k_mlp12(const float* __restrict__ abuf,
                                                  const float* __restrict__ yts,
                                                  const ushort* __restrict__ W2F,
                                                  const float* __restrict__ b2,
                                                  const ushort* __restrict__ W3F,
                                                  const float* __restrict__ b3,
                                                  float* __restrict__ out) {
    __shared__ char lds[65536];    // H1 [4 kp][64 r][128 kk] bf16; then h2 frag slices
    int b = blockIdx.x, t0 = blockIdx.y * 64, tid = threadIdx.x;
    const float* a0p = abuf + (size_t)b * 3 * HID;
    const float* a1p = a0p + HID;
    const float* a2p = a1p + HID;

    {
        int sr = tid & 63, sub0 = (tid >> 6) & 1, skp = tid >> 7;
        float t = yts[(size_t)b * TT + t0 + sr];
        int kg0 = skp * 128 + sub0 * 64;
        uint sbase = (uint)(skp * 16384 + sr * 256 + sub0 * 128);
        #pragma unroll
        for (int i = 0; i < 8; ++i) {
            int k = kg0 + i * 8;
            float4 xa0 = *(const float4*)(a0p + k), xb0 = *(const float4*)(a0p + k + 4);
            float4 xa1 = *(const float4*)(a1p + k), xb1 = *(const float4*)(a1p + k + 4);
            float4 xa2 = *(const float4*)(a2p + k), xb2 = *(const float4*)(a2p + k + 4);
            uint4 pk;
            pk.x = pk2(h1f(xa0.x, xa1.x, xa2.x, t), h1f(xa0.y, xa1.y, xa2.y, t));
            pk.y = pk2(h1f(xa0.z, xa1.z, xa2.z, t), h1f(xa0.w, xa1.w, xa2.w, t));
            pk.z = pk2(h1f(xb0.x, xb1.x, xb2.x, t), h1f(xb0.y, xb1.y, xb2.y, t));
            pk.w = pk2(h1f(xb0.z, xb1.z, xb2.z, t), h1f(xb0.w, xb1.w, xb2.w, t));
            *(uint4*)(lds + swz(sbase + i * 16)) = pk;
        }
    }
    __syncthreads();

    int lane = tid & 63, w = tid >> 6;
    int l31 = lane & 31, hl = lane >> 5;
    int wp = w & 1, gw = w >> 1;
    int Jb = gw * 4 + wp * 2;

    f32x16 acc[2][2];
    #pragma unroll
    for (int jt = 0; jt < 2; ++jt) {
        int jT = (Jb + jt) * 32;
        #pragma unroll
        for (int reg = 0; reg < 16; ++reg) {
            int slot = (reg & 3) + 8 * (reg >> 2) + 4 * hl;
            float bv = b2[jT + sigma(slot)];
            acc[jt][0][reg] = bv;
            acc[jt][1][reg] = bv;
        }
    }
    #pragma unroll 4
    for (int ks = 0; ks < 32; ++ks) {
        uint base = (uint)((ks >> 3) * 16384 + (ks & 7) * 32 + hl * 16);
        bf16x8 bh0 = *(const bf16x8*)(lds + swz(base + (uint)(l31 * 256)));
        bf16x8 bh1 = *(const bf16x8*)(lds + swz(base + (uint)((32 + l31) * 256)));
        #pragma unroll
        for (int jt = 0; jt < 2; ++jt) {
            bf16x8 af = *(const bf16x8*)(W2F + ((size_t)(ks * 16 + Jb + jt) * 64 + lane) * 8);
            acc[jt][0] = __builtin_amdgcn_mfma_f32_32x32x16_bf16(af, bh0, acc[jt][0], 0, 0, 0);
            acc[jt][1] = __builtin_amdgcn_mfma_f32_32x32x16_bf16(af, bh1, acc[jt][1], 0, 0, 0);
        }
    }
    __syncthreads();

    #pragma unroll
    for (int jt = 0; jt < 2; ++jt) {
        int J = Jb + jt;
        #pragma unroll
        for (int rtile = 0; rtile < 2; ++rtile)
            #pragma unroll
            for (int s = 0; s < 2; ++s) {
                uint4 uu;
                uu.x = pk2(fmaxf(acc[jt][rtile][8 * s + 0], 0.f), fmaxf(acc[jt][rtile][8 * s + 1], 0.f));
                uu.y = pk2(fmaxf(acc[jt][rtile][8 * s + 2], 0.f), fmaxf(acc[jt][rtile][8 * s + 3], 0.f));
                uu.z = pk2(fmaxf(acc[jt][rtile][8 * s + 4], 0.f), fmaxf(acc[jt][rtile][8 * s + 5], 0.f));
                uu.w = pk2(fmaxf(acc[jt][rtile][8 * s + 6], 0.f), fmaxf(acc[jt][rtile][8 * s + 7], 0.f));
                *(uint4*)(lds + (uint)((rtile * 32 + J * 2 + s) * 1024 + lane * 16)) = uu;
            }
    }
    __syncthreads();

    f32x16 acc2a, acc2b;
    {
        float bv = b3[gw * 32 + l31];
        #pragma unroll
        for (int e = 0; e < 16; ++e) { acc2a[e] = bv; acc2b[e] = 0.f; }
    }
    #pragma unroll 4
    for (int sg = 0; sg < 32; sg += 2) {
        {
            bf16x8 ah = *(const bf16x8*)(lds + (uint)((wp * 32 + sg) * 1024 + lane * 16));
            bf16x8 bw = *(const bf16x8*)(W3F + ((size_t)(sg * 4 + gw) * 64 + lane) * 8);
            acc2a = __builtin_amdgcn_mfma_f32_32x32x16_bf16(ah, bw, acc2a, 0, 0, 0);
        }
        {
            bf16x8 ah = *(const bf16x8*)(lds + (uint)((wp * 32 + sg + 1) * 1024 + lane * 16));
            bf16x8 bw = *(const bf16x8*)(W3F + ((size_t)((sg + 1) * 4 + gw) * 64 + lane) * 8);
            acc2b = __builtin_amdgcn_mfma_f32_32x32x16_bf16(ah, bw, acc2b, 0, 0, 0);
        }
    }

    {
        int c = gw * 32 + l31;
        size_t rowbase = (size_t)b * TT + t0 + wp * 32 + 4 * hl;
        #pragma unroll
        for (int reg = 0; reg < 16; ++reg)
            out[(rowbase + (reg & 3) + 8 * (reg >> 2)) * D + c] = acc2a[reg] + acc2b[reg];
    }
}

extern "C" void kernel_launch(void* const* d_in, const int* in_sizes, int n_in,
                              void* d_out, int out_size, void* d_ws, size_t ws_size,
                              hipStream_t stream) {
    const float* timesteps = (const float*)d_in[0];
    const float* X        = (const float*)d_in[1];
    const float* M        = (const float*)d_in[2];
    const float* yts      = (const float*)d_in[3];
    const float* w_te     = (const float*)d_in[4];
    const float* b_te     = (const float*)d_in[5];
    const float* query    = (const float*)d_in[6];
    const float* W_q      = (const float*)d_in[7];
    const float* b_q      = (const float*)d_in[8];
    const float* W_k      = (const float*)d_in[9];
    const float* b_k      = (const float*)d_in[10];
    const float* W_o      = (const float*)d_in[11];
    const float* b_o      = (const float*)d_in[12];
    const float* W1       = (const float*)d_in[13];
    const float* b1       = (const float*)d_in[14];
    const float* W2       = (const float*)d_in[15];
    const float* b2       = (const float*)d_in[16];
    const float* W3       = (const float*)d_in[17];
    const float* b3       = (const float*)d_in[18];
    float* out = (float*)d_out;
    float* ws  = (float*)d_ws;

    float* vsin   = ws + OFF_VS;
    float* wA     = ws + OFF_WA;
    float* wB     = ws + OFF_WB;
    float* sbias  = ws + OFF_SB;
    float* cvp    = ws + OFF_CVP;
    float* part2  = ws + OFF_P2;
    ushort* part  = (ushort*)(ws + OFF_PART);
    float* abuf   = ws + OFF_A;
    ushort* W2F   = (ushort*)(ws + OFF_SC);
    ushort* W3F   = W2F + (size_t)HID * HID;

    hipLaunchKernelGGL(k_setup,  dim3(HP + 32 + 80),  dim3(512), 0, stream,
                       query, W_q, b_q, W_k, b_k, w_te, b_te, W_o, W2, W3,
                       vsin, wA, wB, sbias, cvp, W2F, W3F);
    hipLaunchKernelGGL(k_wsf2,   dim3(BB * CH2),      dim3(512), 0, stream,
                       timesteps, w_te, b_te, vsin, wA, wB, sbias, X, M, part);
    hipLaunchKernelGGL(k_mid,    dim3(BB * NH),       dim3(256), 0, stream,
                       part, W_o, cvp, b_o, part2);
    hipLaunchKernelGGL(k_avec4,  dim3(BB, 4),         dim3(128), 0, stream,
                       part2, W1, b1, abuf);
    hipLaunchKernelGGL(k_mlp12,  dim3(BB, TT / 64),   dim3(512), 0, stream,
                       abuf, yts, W2F, b2, W3F, b3, out);
}